// Round 2
// baseline (2106.515 us; speedup 1.0000x reference)
//
#include <hip/hip_runtime.h>
#include <math.h>

// Problem constants (QANetAttBlock): B=16, S=1024, HID=512, H=8, DK=64
constexpr int CB = 16;
constexpr int CS = 1024;
constexpr int CHID = 512;
constexpr int CH = 8;
constexpr int CDK = 64;

// ---------------------------------------------------------------------------
// Kernel 1: per-batch valid length = sum of prefix mask row
// ---------------------------------------------------------------------------
__global__ __launch_bounds__(256) void lengths_kernel(const int* __restrict__ mask,
                                                      int* __restrict__ lens) {
  const int b = blockIdx.x;
  const int t = threadIdx.x;
  __shared__ int red[256];
  int s = 0;
  for (int i = t; i < CS; i += 256) s += mask[b * CS + i];
  red[t] = s;
  __syncthreads();
  for (int off = 128; off > 0; off >>= 1) {
    if (t < off) red[t] += red[t + off];
    __syncthreads();
  }
  if (t == 0) lens[b] = red[0];
}

// ---------------------------------------------------------------------------
// Kernel 2: QKV projection.  X[B*S, HID] @ W[h][HID, DK] -> {Q,K,V}[B,H,S,DK]
// grid = (256 row-tiles of 64, 24 = which*8+h), block = 256
// ---------------------------------------------------------------------------
__global__ __launch_bounds__(256) void qkv_proj_kernel(
    const float* __restrict__ x, const float* __restrict__ Wq,
    const float* __restrict__ Wk, const float* __restrict__ Wv,
    float* __restrict__ Q, float* __restrict__ K, float* __restrict__ V) {
  const int rt = blockIdx.x;
  const int ct = blockIdx.y;
  const int which = ct >> 3, h = ct & 7;
  const float* W = (which == 0) ? Wq : (which == 1) ? Wk : Wv;
  W += (size_t)h * CHID * CDK;
  float* O = (which == 0) ? Q : (which == 1) ? K : V;

  const int row0 = rt * 64;
  const int t = threadIdx.x;
  __shared__ float xs[64][17];  // [row][k] chunk, pad to 17 to break conflicts
  __shared__ float ws[16][64];

  float acc[4][4];
#pragma unroll
  for (int i = 0; i < 4; ++i)
#pragma unroll
    for (int j = 0; j < 4; ++j) acc[i][j] = 0.f;

  const int tr = t >> 4, tc = t & 15;

  for (int k0 = 0; k0 < CHID; k0 += 16) {
    {
      const int col = t & 15, r = t >> 4;
#pragma unroll
      for (int i = 0; i < 4; ++i)
        xs[r + 16 * i][col] = x[(size_t)(row0 + r + 16 * i) * CHID + k0 + col];
    }
    {
      const int col = t & 63, rw = t >> 6;
#pragma unroll
      for (int i = 0; i < 4; ++i)
        ws[rw + 4 * i][col] = W[(size_t)(k0 + rw + 4 * i) * CDK + col];
    }
    __syncthreads();
#pragma unroll
    for (int kk = 0; kk < 16; ++kk) {
      float a[4], bb[4];
#pragma unroll
      for (int i = 0; i < 4; ++i) a[i] = xs[tr * 4 + i][kk];
#pragma unroll
      for (int j = 0; j < 4; ++j) bb[j] = ws[kk][tc * 4 + j];
#pragma unroll
      for (int i = 0; i < 4; ++i)
#pragma unroll
        for (int j = 0; j < 4; ++j) acc[i][j] += a[i] * bb[j];
    }
    __syncthreads();
  }

  // write out: row r = b*S + s -> O[((b*H + h)*S + s)*DK + dk]
#pragma unroll
  for (int i = 0; i < 4; ++i) {
    const int r = row0 + tr * 4 + i;
    const int b = r >> 10, s = r & 1023;
    const size_t base = (((size_t)b * CH + h) * CS + s) * CDK;
#pragma unroll
    for (int j = 0; j < 4; ++j) O[base + tc * 4 + j] = acc[i][j];
  }
}

// ---------------------------------------------------------------------------
// Kernel 3: flash-style attention per (q-tile of 64, h, b).
// Semantics matched to reference:
//   valid q (q < n):  softmax over k of (QK/sqrt(n) if k<n else -1e30)
//   invalid q (q>=n): all scores -1e30 -> softmax uniform over ALL S -> mean(V)
//     (reproduced by s = 0 for every k)
// block = 256 threads = 64 rows x 4 quarters; each thread: 16 k-cols / 16 dk
// ---------------------------------------------------------------------------
__global__ __launch_bounds__(256) void attn_kernel(
    const float* __restrict__ Q, const float* __restrict__ K,
    const float* __restrict__ V, const int* __restrict__ lens,
    float* __restrict__ Hb) {
  const int qt = blockIdx.x, h = blockIdx.y, b = blockIdx.z;
  const int n = lens[b];
  const float inv_sqrt_n = rsqrtf((float)n);
  const int t = threadIdx.x;
  const int q = t >> 2, c = t & 3;

  __shared__ float Qs[64][65];
  __shared__ float KsSc[64][65];  // K chunk during scores, then P tile
  __shared__ float Vs[64][65];

  const size_t bh = ((size_t)b * CH + h) * CS;

  {
    const int d = t & 63, r0 = t >> 6;
#pragma unroll
    for (int i = 0; i < 16; ++i) {
      const int row = r0 + 4 * i;
      Qs[row][d] = Q[(bh + qt * 64 + row) * CDK + d];
    }
  }

  float m = -3.0e38f, l = 0.f;
  float acc[16];
#pragma unroll
  for (int i = 0; i < 16; ++i) acc[i] = 0.f;

  const int q_abs = qt * 64 + q;
  const bool qvalid = q_abs < n;

  for (int kt = 0; kt < CS / 64; ++kt) {
    __syncthreads();  // previous PV reads of KsSc/Vs complete
    {
      const int d = t & 63, r0 = t >> 6;
#pragma unroll
      for (int i = 0; i < 16; ++i) {
        const int row = r0 + 4 * i;
        const size_t g = (bh + kt * 64 + row) * CDK + d;
        KsSc[row][d] = K[g];
        Vs[row][d] = V[g];
      }
    }
    __syncthreads();

    // scores for this thread's 16 k columns
    float sl[16];
#pragma unroll
    for (int j = 0; j < 16; ++j) sl[j] = 0.f;
    for (int d = 0; d < 64; ++d) {
      const float qd = Qs[q][d];
#pragma unroll
      for (int j = 0; j < 16; ++j) sl[j] += qd * KsSc[c * 16 + j][d];
    }
    float mc = -3.0e38f;
#pragma unroll
    for (int j = 0; j < 16; ++j) {
      const int k_abs = kt * 64 + c * 16 + j;
      const float s = qvalid ? ((k_abs < n) ? sl[j] * inv_sqrt_n : -1.0e30f) : 0.f;
      sl[j] = s;
      mc = fmaxf(mc, s);
    }
    // reduce max / sum across the 4 threads of this row (same wave: t = 4q+c)
    mc = fmaxf(mc, __shfl_xor(mc, 1));
    mc = fmaxf(mc, __shfl_xor(mc, 2));
    const float mnew = fmaxf(m, mc);
    const float alpha = __expf(m - mnew);  // first chunk: exp(-3e38-x) = 0
    float lc = 0.f;
#pragma unroll
    for (int j = 0; j < 16; ++j) {
      const float p = __expf(sl[j] - mnew);
      sl[j] = p;
      lc += p;
    }
    lc += __shfl_xor(lc, 1);
    lc += __shfl_xor(lc, 2);
    l = l * alpha + lc;
    m = mnew;

    __syncthreads();  // all K reads of KsSc done before overwrite with P
#pragma unroll
    for (int j = 0; j < 16; ++j) KsSc[q][c * 16 + j] = sl[j];
    __syncthreads();

#pragma unroll
    for (int i = 0; i < 16; ++i) acc[i] *= alpha;
    for (int k = 0; k < 64; ++k) {
      const float p = KsSc[q][k];
#pragma unroll
      for (int i = 0; i < 16; ++i) acc[i] += p * Vs[k][c * 16 + i];
    }
  }

  const float invl = 1.0f / l;
  __syncthreads();  // PV done; reuse Qs as output staging
#pragma unroll
  for (int i = 0; i < 16; ++i) Qs[q][c * 16 + i] = acc[i] * invl;
  __syncthreads();
  {
    const int d = t & 63, r0 = t >> 6;
#pragma unroll
    for (int i = 0; i < 16; ++i) {
      const int row = r0 + 4 * i;
      Hb[((size_t)b * CS + qt * 64 + row) * (CH * CDK) + h * 64 + d] = Qs[row][d];
    }
  }
}

// ---------------------------------------------------------------------------
// Kernel 4: output projection.  Hb[B*S, 512] @ Wout[512, 512] -> out
// grid = (256 row-tiles, 8 col-tiles of 64), block = 256
// ---------------------------------------------------------------------------
__global__ __launch_bounds__(256) void out_proj_kernel(
    const float* __restrict__ Hb, const float* __restrict__ Wout,
    float* __restrict__ out) {
  const int rt = blockIdx.x, ct = blockIdx.y;
  const int row0 = rt * 64, col0 = ct * 64;
  const int t = threadIdx.x;
  __shared__ float hs[64][17];
  __shared__ float ws[16][64];

  float acc[4][4];
#pragma unroll
  for (int i = 0; i < 4; ++i)
#pragma unroll
    for (int j = 0; j < 4; ++j) acc[i][j] = 0.f;

  const int tr = t >> 4, tc = t & 15;

  for (int k0 = 0; k0 < CH * CDK; k0 += 16) {
    {
      const int col = t & 15, r = t >> 4;
#pragma unroll
      for (int i = 0; i < 4; ++i)
        hs[r + 16 * i][col] =
            Hb[(size_t)(row0 + r + 16 * i) * (CH * CDK) + k0 + col];
    }
    {
      const int col = t & 63, rw = t >> 6;
#pragma unroll
      for (int i = 0; i < 4; ++i)
        ws[rw + 4 * i][col] = Wout[(size_t)(k0 + rw + 4 * i) * CHID + col0 + col];
    }
    __syncthreads();
#pragma unroll
    for (int kk = 0; kk < 16; ++kk) {
      float a[4], bb[4];
#pragma unroll
      for (int i = 0; i < 4; ++i) a[i] = hs[tr * 4 + i][kk];
#pragma unroll
      for (int j = 0; j < 4; ++j) bb[j] = ws[kk][tc * 4 + j];
#pragma unroll
      for (int i = 0; i < 4; ++i)
#pragma unroll
        for (int j = 0; j < 4; ++j) acc[i][j] += a[i] * bb[j];
    }
    __syncthreads();
  }

#pragma unroll
  for (int i = 0; i < 4; ++i) {
    const size_t r = row0 + tr * 4 + i;
#pragma unroll
    for (int j = 0; j < 4; ++j)
      out[r * CHID + col0 + tc * 4 + j] = acc[i][j];
  }
}

// ---------------------------------------------------------------------------
extern "C" void kernel_launch(void* const* d_in, const int* in_sizes, int n_in,
                              void* d_out, int out_size, void* d_ws,
                              size_t ws_size, hipStream_t stream) {
  const float* x = (const float*)d_in[0];
  const int* mask = (const int*)d_in[1];
  const float* Wq = (const float*)d_in[2];
  const float* Wk = (const float*)d_in[3];
  const float* Wv = (const float*)d_in[4];
  const float* Wout = (const float*)d_in[5];
  float* out = (float*)d_out;

  // workspace layout (floats): [lens(1024 slots incl. pad)] [Q] [K] [V] [Hb]
  int* lens = (int*)d_ws;
  float* ws_f = (float*)d_ws;
  const size_t NQ = (size_t)CB * CH * CS * CDK;  // 8,388,608
  float* Qb = ws_f + 1024;
  float* Kb = Qb + NQ;
  float* Vb = Kb + NQ;
  float* Hb = Vb + NQ;

  lengths_kernel<<<CB, 256, 0, stream>>>(mask, lens);

  dim3 g1(256, 24);
  qkv_proj_kernel<<<g1, 256, 0, stream>>>(x, Wq, Wk, Wv, Qb, Kb, Vb);

  dim3 g2(CS / 64, CH, CB);
  attn_kernel<<<g2, 256, 0, stream>>>(Qb, Kb, Vb, lens, Hb);

  dim3 g3(256, 8);
  out_proj_kernel<<<g3, 256, 0, stream>>>(Hb, Wout, out);
}

// Round 3
// 280.131 us; speedup vs baseline: 7.5197x; 7.5197x over previous
//
#include <hip/hip_runtime.h>
#include <math.h>

// QANetAttBlock: B=16, S=1024, HID=512, H=8, DK=64
constexpr int CB = 16;
constexpr int CS = 1024;
constexpr int CHID = 512;
constexpr int CH = 8;
constexpr int CDK = 64;

typedef _Float16 f16;
typedef __attribute__((ext_vector_type(8))) _Float16 f16x8;
typedef __attribute__((ext_vector_type(4))) _Float16 f16x4;
typedef __attribute__((ext_vector_type(4))) float f32x4;

__device__ inline f32x4 mfma16(f16x8 a, f16x8 b, f32x4 c) {
  return __builtin_amdgcn_mfma_f32_16x16x32_f16(a, b, c, 0, 0, 0);
}

// ---------------------------------------------------------------------------
// lengths: per-batch prefix-mask sum
// ---------------------------------------------------------------------------
__global__ __launch_bounds__(256) void lengths_kernel(const int* __restrict__ mask,
                                                      int* __restrict__ lens) {
  const int b = blockIdx.x, t = threadIdx.x;
  __shared__ int red[256];
  int s = 0;
  for (int i = t; i < CS; i += 256) s += mask[b * CS + i];
  red[t] = s;
  __syncthreads();
  for (int off = 128; off > 0; off >>= 1) {
    if (t < off) red[t] += red[t + off];
    __syncthreads();
  }
  if (t == 0) lens[b] = red[0];
}

// ---------------------------------------------------------------------------
// cast x (fp32 -> fp16), vectorized
// ---------------------------------------------------------------------------
__global__ __launch_bounds__(256) void cast_x_kernel(const float4* __restrict__ x,
                                                     f16x4* __restrict__ xh) {
  const int idx = blockIdx.x * 256 + threadIdx.x;
  const float4 v = x[idx];
  f16x4 o;
  o[0] = (f16)v.x; o[1] = (f16)v.y; o[2] = (f16)v.z; o[3] = (f16)v.w;
  xh[idx] = o;
}

// ---------------------------------------------------------------------------
// cast + transpose weights.
// y in 0..2: W[y] is [8][512][64] (h,k,n) -> wtAll + y*262144 as [8][64][512] (h,n,k)
// y == 3:    Wout [512][512] (k,n)       -> wtAll + 3*262144 as [512][512] (n,k)
// grid (256,4) x 256 threads, 4 outputs/thread (consecutive k)
// ---------------------------------------------------------------------------
__global__ __launch_bounds__(256) void cast_w_kernel(const float* __restrict__ Wq,
                                                     const float* __restrict__ Wk,
                                                     const float* __restrict__ Wv,
                                                     const float* __restrict__ Wout,
                                                     f16* __restrict__ wtAll) {
  const int y = blockIdx.y;
  const int o0 = (blockIdx.x * 256 + threadIdx.x) * 4;
  f16* D = wtAll + (size_t)y * 262144;
  f16x4 d;
  if (y < 3) {
    const float* W = (y == 0) ? Wq : (y == 1) ? Wk : Wv;
    const int h = o0 >> 15, n = (o0 >> 9) & 63, k = o0 & 511;
    const size_t in = (size_t)h * 32768 + (size_t)k * 64 + n;
#pragma unroll
    for (int j = 0; j < 4; ++j) d[j] = (f16)W[in + (size_t)j * 64];
  } else {
    const int n = o0 >> 9, k = o0 & 511;
#pragma unroll
    for (int j = 0; j < 4; ++j) d[j] = (f16)Wout[(size_t)(k + j) * 512 + n];
  }
  *(f16x4*)&D[o0] = d;
}

// ---------------------------------------------------------------------------
// QKV projection (MFMA): C[16384,64] = xh[16384,512] @ W[h][512,64]
// grid (128 row-tiles of 128, 24 = which*8+h), block 256 (4 waves, 2x2)
// Q,K -> [B,H,S,64] fp16 ; V -> transposed [B,H,64,S] fp16
// ---------------------------------------------------------------------------
__global__ __launch_bounds__(256) void qkv_kernel(
    const f16* __restrict__ xh, const f16* __restrict__ wtAll,
    f16* __restrict__ Qh, f16* __restrict__ Kh, f16* __restrict__ Vth) {
  const int rt = blockIdx.x;
  const int which = blockIdx.y >> 3, h = blockIdx.y & 7;
  const f16* Wt = wtAll + (size_t)which * 262144 + (size_t)h * CDK * CHID;  // [64n][512k]
  const int row0 = rt * 128;
  const int t = threadIdx.x;
  const int w = t >> 6, lane = t & 63, quad = lane >> 4, lcol = lane & 15;
  const int wr = w >> 1, wc = w & 1;

  __shared__ f16 Xs[128][40];  // stride 40 f16 = 80 B (16B-aligned rows, ~2-way banks)
  __shared__ f16 Ws[64][40];

  f32x4 acc[4][2];
#pragma unroll
  for (int i = 0; i < 4; ++i)
#pragma unroll
    for (int j = 0; j < 2; ++j) acc[i][j] = (f32x4){0.f, 0.f, 0.f, 0.f};

  for (int k0 = 0; k0 < CHID; k0 += 32) {
#pragma unroll
    for (int i = 0; i < 2; ++i) {
      const int c = t + 256 * i, r = c >> 2, sg = c & 3;
      *(f16x8*)&Xs[r][sg * 8] =
          *(const f16x8*)&xh[(size_t)(row0 + r) * CHID + k0 + sg * 8];
    }
    {
      const int r = t >> 2, sg = t & 3;
      *(f16x8*)&Ws[r][sg * 8] =
          *(const f16x8*)&Wt[(size_t)r * CHID + k0 + sg * 8];
    }
    __syncthreads();
    f16x8 af[4], bf[2];
#pragma unroll
    for (int i = 0; i < 4; ++i)
      af[i] = *(const f16x8*)&Xs[wr * 64 + i * 16 + lcol][quad * 8];
#pragma unroll
    for (int j = 0; j < 2; ++j)
      bf[j] = *(const f16x8*)&Ws[wc * 32 + j * 16 + lcol][quad * 8];
#pragma unroll
    for (int i = 0; i < 4; ++i)
#pragma unroll
      for (int j = 0; j < 2; ++j) acc[i][j] = mfma16(af[i], bf[j], acc[i][j]);
    __syncthreads();
  }

#pragma unroll
  for (int i = 0; i < 4; ++i) {
#pragma unroll
    for (int rr = 0; rr < 4; ++rr) {
      const int rg = row0 + wr * 64 + i * 16 + quad * 4 + rr;
      const int b = rg >> 10, s = rg & 1023;
#pragma unroll
      for (int j = 0; j < 2; ++j) {
        const int d = wc * 32 + j * 16 + lcol;
        const f16 v = (f16)acc[i][j][rr];
        if (which == 2)
          Vth[(((size_t)b * CH + h) * CDK + d) * CS + s] = v;
        else if (which == 0)
          Qh[(((size_t)b * CH + h) * CS + s) * CDK + d] = v;
        else
          Kh[(((size_t)b * CH + h) * CS + s) * CDK + d] = v;
      }
    }
  }
}

// ---------------------------------------------------------------------------
// Attention (MFMA flash, no-max softmax — scores are O(1) so exp is safe;
// masked -> exp(-1e30)=0; invalid q rows -> s=0 -> uniform = reference).
// grid (16 q-tiles, 8 heads, 16 batch), block 256 = 4 waves x 16 q-rows.
// ---------------------------------------------------------------------------
__global__ __launch_bounds__(256) void attn_kernel(
    const f16* __restrict__ Qh, const f16* __restrict__ Kh,
    const f16* __restrict__ Vth, const int* __restrict__ lens,
    f16* __restrict__ Hbh) {
  const int qt = blockIdx.x, h = blockIdx.y, b = blockIdx.z;
  const int n = lens[b];
  const float inv_sqrt_n = rsqrtf((float)n);
  const int t = threadIdx.x, w = t >> 6, lane = t & 63, quad = lane >> 4,
            lcol = lane & 15;

  __shared__ f16 Ks[64][72];     // [k][d], stride 144B
  __shared__ f16 Vs[64][72];     // V^T: [d][k]
  __shared__ float Pt[4][16][68];  // wave-private P, stride 272B

  const size_t bh = ((size_t)b * CH + h) * CS;
  const size_t bhd = ((size_t)b * CH + h) * CDK;

  const int qrow = qt * 64 + w * 16 + lcol;
  const f16x8 qa0 = *(const f16x8*)&Qh[(bh + qrow) * CDK + quad * 8];
  const f16x8 qa1 = *(const f16x8*)&Qh[(bh + qrow) * CDK + 32 + quad * 8];

  f32x4 o[4];
#pragma unroll
  for (int dt = 0; dt < 4; ++dt) o[dt] = (f32x4){0.f, 0.f, 0.f, 0.f};
  float lp[4] = {0.f, 0.f, 0.f, 0.f};
  bool qv[4];
#pragma unroll
  for (int r = 0; r < 4; ++r) qv[r] = (qt * 64 + w * 16 + quad * 4 + r) < n;

  for (int kt = 0; kt < CS / 64; ++kt) {
    __syncthreads();  // prior PV reads of Ks/Vs done
#pragma unroll
    for (int i = 0; i < 2; ++i) {
      const int c = t + 256 * i, r = c >> 3, sg = c & 7;
      *(f16x8*)&Ks[r][sg * 8] =
          *(const f16x8*)&Kh[(bh + kt * 64 + r) * CDK + sg * 8];
      *(f16x8*)&Vs[r][sg * 8] =
          *(const f16x8*)&Vth[(bhd + r) * CS + kt * 64 + sg * 8];
    }
    __syncthreads();

    f32x4 s[4];
#pragma unroll
    for (int ct = 0; ct < 4; ++ct) s[ct] = (f32x4){0.f, 0.f, 0.f, 0.f};
#pragma unroll
    for (int ct = 0; ct < 4; ++ct) {
      const f16x8 kb0 = *(const f16x8*)&Ks[ct * 16 + lcol][quad * 8];
      const f16x8 kb1 = *(const f16x8*)&Ks[ct * 16 + lcol][32 + quad * 8];
      s[ct] = mfma16(qa0, kb0, s[ct]);
      s[ct] = mfma16(qa1, kb1, s[ct]);
    }

    // mask + exp (no max subtraction needed: |s|/sqrt(n) is O(1))
#pragma unroll
    for (int ct = 0; ct < 4; ++ct) {
      const bool kvld = (kt * 64 + ct * 16 + lcol) < n;
#pragma unroll
      for (int r = 0; r < 4; ++r) {
        const float sv = qv[r] ? (kvld ? s[ct][r] * inv_sqrt_n : -1.0e30f) : 0.f;
        const float p = __expf(sv);
        lp[r] += p;
        Pt[w][quad * 4 + r][ct * 16 + lcol] = p;  // C-layout -> [q][k]
      }
    }

    // P -> A-operand frags (wave-private LDS round-trip)
    f16x8 pa0, pa1;
    {
      const float* pr = &Pt[w][lcol][quad * 8];
      const float4 u0 = *(const float4*)pr;
      const float4 u1 = *(const float4*)(pr + 4);
      pa0[0] = (f16)u0.x; pa0[1] = (f16)u0.y; pa0[2] = (f16)u0.z; pa0[3] = (f16)u0.w;
      pa0[4] = (f16)u1.x; pa0[5] = (f16)u1.y; pa0[6] = (f16)u1.z; pa0[7] = (f16)u1.w;
      const float* pr2 = &Pt[w][lcol][32 + quad * 8];
      const float4 v0 = *(const float4*)pr2;
      const float4 v1 = *(const float4*)(pr2 + 4);
      pa1[0] = (f16)v0.x; pa1[1] = (f16)v0.y; pa1[2] = (f16)v0.z; pa1[3] = (f16)v0.w;
      pa1[4] = (f16)v1.x; pa1[5] = (f16)v1.y; pa1[6] = (f16)v1.z; pa1[7] = (f16)v1.w;
    }

#pragma unroll
    for (int dt = 0; dt < 4; ++dt) {
      const f16x8 vb0 = *(const f16x8*)&Vs[dt * 16 + lcol][quad * 8];
      const f16x8 vb1 = *(const f16x8*)&Vs[dt * 16 + lcol][32 + quad * 8];
      o[dt] = mfma16(pa0, vb0, o[dt]);
      o[dt] = mfma16(pa1, vb1, o[dt]);
    }
  }

  float invl[4];
#pragma unroll
  for (int r = 0; r < 4; ++r) {
    float v = lp[r];
    v += __shfl_xor(v, 1);
    v += __shfl_xor(v, 2);
    v += __shfl_xor(v, 4);
    v += __shfl_xor(v, 8);
    invl[r] = 1.0f / v;
  }
#pragma unroll
  for (int dt = 0; dt < 4; ++dt)
#pragma unroll
    for (int r = 0; r < 4; ++r) {
      const int srow = qt * 64 + w * 16 + quad * 4 + r;
      Hbh[((size_t)b * CS + srow) * (CH * CDK) + h * CDK + dt * 16 + lcol] =
          (f16)(o[dt][r] * invl[r]);
    }
}

// ---------------------------------------------------------------------------
// Output projection (MFMA): out[16384,512] = Hbh[16384,512] @ Wout[512,512]
// grid (128 row-tiles, 8 col-tiles of 64), block 256
// ---------------------------------------------------------------------------
__global__ __launch_bounds__(256) void outp_kernel(const f16* __restrict__ Hbh,
                                                   const f16* __restrict__ woutt,
                                                   float* __restrict__ out) {
  const int rt = blockIdx.x, ctile = blockIdx.y;
  const int row0 = rt * 128, col0 = ctile * 64;
  const f16* Wt = woutt + (size_t)col0 * CHID;  // [64n][512k]
  const int t = threadIdx.x;
  const int w = t >> 6, lane = t & 63, quad = lane >> 4, lcol = lane & 15;
  const int wr = w >> 1, wc = w & 1;

  __shared__ f16 Hs[128][40];
  __shared__ f16 Ws[64][40];

  f32x4 acc[4][2];
#pragma unroll
  for (int i = 0; i < 4; ++i)
#pragma unroll
    for (int j = 0; j < 2; ++j) acc[i][j] = (f32x4){0.f, 0.f, 0.f, 0.f};

  for (int k0 = 0; k0 < CHID; k0 += 32) {
#pragma unroll
    for (int i = 0; i < 2; ++i) {
      const int c = t + 256 * i, r = c >> 2, sg = c & 3;
      *(f16x8*)&Hs[r][sg * 8] =
          *(const f16x8*)&Hbh[(size_t)(row0 + r) * CHID + k0 + sg * 8];
    }
    {
      const int r = t >> 2, sg = t & 3;
      *(f16x8*)&Ws[r][sg * 8] =
          *(const f16x8*)&Wt[(size_t)r * CHID + k0 + sg * 8];
    }
    __syncthreads();
    f16x8 af[4], bf[2];
#pragma unroll
    for (int i = 0; i < 4; ++i)
      af[i] = *(const f16x8*)&Hs[wr * 64 + i * 16 + lcol][quad * 8];
#pragma unroll
    for (int j = 0; j < 2; ++j)
      bf[j] = *(const f16x8*)&Ws[wc * 32 + j * 16 + lcol][quad * 8];
#pragma unroll
    for (int i = 0; i < 4; ++i)
#pragma unroll
      for (int j = 0; j < 2; ++j) acc[i][j] = mfma16(af[i], bf[j], acc[i][j]);
    __syncthreads();
  }

#pragma unroll
  for (int i = 0; i < 4; ++i) {
#pragma unroll
    for (int rr = 0; rr < 4; ++rr) {
      const size_t rg = row0 + wr * 64 + i * 16 + quad * 4 + rr;
#pragma unroll
      for (int j = 0; j < 2; ++j)
        out[rg * CHID + col0 + wc * 32 + j * 16 + lcol] = acc[i][j][rr];
    }
  }
}

// ---------------------------------------------------------------------------
extern "C" void kernel_launch(void* const* d_in, const int* in_sizes, int n_in,
                              void* d_out, int out_size, void* d_ws,
                              size_t ws_size, hipStream_t stream) {
  const float* x = (const float*)d_in[0];
  const int* mask = (const int*)d_in[1];
  const float* Wq = (const float*)d_in[2];
  const float* Wk = (const float*)d_in[3];
  const float* Wv = (const float*)d_in[4];
  const float* Wout = (const float*)d_in[5];
  float* out = (float*)d_out;

  char* ws = (char*)d_ws;
  int* lens = (int*)ws;
  size_t off = 1024;
  const size_t NX = (size_t)CB * CS * CHID;      // 8,388,608
  const size_t NW = (size_t)CH * CHID * CDK;     // 262,144 per weight
  f16* xh = (f16*)(ws + off);   off += NX * 2;
  f16* wtAll = (f16*)(ws + off); off += NW * 4 * 2;  // Wq^T,Wk^T,Wv^T,Wout^T
  f16* Qh = (f16*)(ws + off);   off += NX * 2;
  f16* Kh = (f16*)(ws + off);   off += NX * 2;
  f16* Vth = (f16*)(ws + off);  off += NX * 2;
  f16* Hbh = (f16*)(ws + off);  off += NX * 2;
  f16* woutt = wtAll + NW * 3;

  lengths_kernel<<<CB, 256, 0, stream>>>(mask, lens);
  cast_x_kernel<<<NX / 4 / 256, 256, 0, stream>>>((const float4*)x, (f16x4*)xh);
  cast_w_kernel<<<dim3(256, 4), 256, 0, stream>>>(Wq, Wk, Wv, Wout, wtAll);
  qkv_kernel<<<dim3(128, 24), 256, 0, stream>>>(xh, wtAll, Qh, Kh, Vth);
  attn_kernel<<<dim3(CS / 64, CH, CB), 256, 0, stream>>>(Qh, Kh, Vth, lens, Hbh);
  outp_kernel<<<dim3(128, 8), 256, 0, stream>>>(Hbh, woutt, out);
}

// Round 5
// 255.260 us; speedup vs baseline: 8.2524x; 1.0974x over previous
//
#include <hip/hip_runtime.h>
#include <math.h>

// QANetAttBlock: B=16, S=1024, HID=512, H=8, DK=64
constexpr int CB = 16;
constexpr int CS = 1024;
constexpr int CHID = 512;
constexpr int CH = 8;
constexpr int CDK = 64;

typedef _Float16 f16;
typedef __attribute__((ext_vector_type(8))) _Float16 f16x8;
typedef __attribute__((ext_vector_type(4))) _Float16 f16x4;
typedef __attribute__((ext_vector_type(4))) float f32x4;

__device__ inline f32x4 mfma16(f16x8 a, f16x8 b, f32x4 c) {
  return __builtin_amdgcn_mfma_f32_16x16x32_f16(a, b, c, 0, 0, 0);
}

// ---------------------------------------------------------------------------
// lengths: per-batch prefix-mask sum
// ---------------------------------------------------------------------------
__global__ __launch_bounds__(256) void lengths_kernel(const int* __restrict__ mask,
                                                      int* __restrict__ lens) {
  const int b = blockIdx.x, t = threadIdx.x;
  __shared__ int red[256];
  int s = 0;
  for (int i = t; i < CS; i += 256) s += mask[b * CS + i];
  red[t] = s;
  __syncthreads();
  for (int off = 128; off > 0; off >>= 1) {
    if (t < off) red[t] += red[t + off];
    __syncthreads();
  }
  if (t == 0) lens[b] = red[0];
}

// ---------------------------------------------------------------------------
// cast x (fp32 -> fp16)
// ---------------------------------------------------------------------------
__global__ __launch_bounds__(256) void cast_x_kernel(const float4* __restrict__ x,
                                                     f16x4* __restrict__ xh) {
  const int idx = blockIdx.x * 256 + threadIdx.x;
  const float4 v = x[idx];
  f16x4 o;
  o[0] = (f16)v.x; o[1] = (f16)v.y; o[2] = (f16)v.z; o[3] = (f16)v.w;
  xh[idx] = o;
}

// ---------------------------------------------------------------------------
// cast + transpose weights
// y in 0..2: W[y] [8][512][64] (h,k,n) -> [8][64][512] (h,n,k)
// y == 3:    Wout [512][512] (k,n)     -> [512][512] (n,k)
// ---------------------------------------------------------------------------
__global__ __launch_bounds__(256) void cast_w_kernel(const float* __restrict__ Wq,
                                                     const float* __restrict__ Wk,
                                                     const float* __restrict__ Wv,
                                                     const float* __restrict__ Wout,
                                                     f16* __restrict__ wtAll) {
  const int y = blockIdx.y;
  const int o0 = (blockIdx.x * 256 + threadIdx.x) * 4;
  f16* D = wtAll + (size_t)y * 262144;
  f16x4 d;
  if (y < 3) {
    const float* W = (y == 0) ? Wq : (y == 1) ? Wk : Wv;
    const int h = o0 >> 15, n = (o0 >> 9) & 63, k = o0 & 511;
    const size_t in = (size_t)h * 32768 + (size_t)k * 64 + n;
#pragma unroll
    for (int j = 0; j < 4; ++j) d[j] = (f16)W[in + (size_t)j * 64];
  } else {
    const int n = o0 >> 9, k = o0 & 511;
#pragma unroll
    for (int j = 0; j < 4; ++j) d[j] = (f16)Wout[(size_t)(k + j) * 512 + n];
  }
  *(f16x4*)&D[o0] = d;
}

// ---------------------------------------------------------------------------
// QKV projection (MFMA). Q pre-scaled by 1/sqrt(n[b]) in fp32.
// V transposed through LDS, stored coalesced as V^T [B,H,64,S].
// grid (128 row-tiles of 128, 24 = which*8+h), block 256 (4 waves, 2x2)
// ---------------------------------------------------------------------------
__global__ __launch_bounds__(256) void qkv_kernel(
    const f16* __restrict__ xh, const f16* __restrict__ wtAll,
    const int* __restrict__ lens, f16* __restrict__ Qh, f16* __restrict__ Kh,
    f16* __restrict__ Vth) {
  const int rt = blockIdx.x;
  const int which = blockIdx.y >> 3, h = blockIdx.y & 7;
  const f16* Wt = wtAll + (size_t)which * 262144 + (size_t)h * CDK * CHID;
  const int row0 = rt * 128;
  const int t = threadIdx.x;
  const int w = t >> 6, lane = t & 63, quad = lane >> 4, lcol = lane & 15;
  const int wr = w >> 1, wc = w & 1;

  __shared__ union SM {
    struct { f16 Xs[128][40]; f16 Ws[64][40]; } a;
    f16 Ts[64][136];  // V-transpose staging (epilogue only)
  } sm;

  f32x4 acc[4][2];
#pragma unroll
  for (int i = 0; i < 4; ++i)
#pragma unroll
    for (int j = 0; j < 2; ++j) acc[i][j] = (f32x4){0.f, 0.f, 0.f, 0.f};

  for (int k0 = 0; k0 < CHID; k0 += 32) {
#pragma unroll
    for (int i = 0; i < 2; ++i) {
      const int c = t + 256 * i, r = c >> 2, sg = c & 3;
      *(f16x8*)&sm.a.Xs[r][sg * 8] =
          *(const f16x8*)&xh[(size_t)(row0 + r) * CHID + k0 + sg * 8];
    }
    {
      const int r = t >> 2, sg = t & 3;
      *(f16x8*)&sm.a.Ws[r][sg * 8] =
          *(const f16x8*)&Wt[(size_t)r * CHID + k0 + sg * 8];
    }
    __syncthreads();
    f16x8 af[4], bf[2];
#pragma unroll
    for (int i = 0; i < 4; ++i)
      af[i] = *(const f16x8*)&sm.a.Xs[wr * 64 + i * 16 + lcol][quad * 8];
#pragma unroll
    for (int j = 0; j < 2; ++j)
      bf[j] = *(const f16x8*)&sm.a.Ws[wc * 32 + j * 16 + lcol][quad * 8];
#pragma unroll
    for (int i = 0; i < 4; ++i)
#pragma unroll
      for (int j = 0; j < 2; ++j) acc[i][j] = mfma16(af[i], bf[j], acc[i][j]);
    __syncthreads();
  }

  const int b = row0 >> 10, s0 = row0 & 1023;
  if (which == 2) {
    // transpose 128s x 64d tile through LDS, store V^T coalesced
#pragma unroll
    for (int i = 0; i < 4; ++i)
#pragma unroll
      for (int rr = 0; rr < 4; ++rr)
#pragma unroll
        for (int j = 0; j < 2; ++j)
          sm.Ts[wc * 32 + j * 16 + lcol][wr * 64 + i * 16 + quad * 4 + rr] =
              (f16)acc[i][j][rr];
    __syncthreads();
#pragma unroll
    for (int i2 = 0; i2 < 4; ++i2) {
      const int chunk = t + 256 * i2;  // 0..1023
      const int r = chunk >> 4, cb = chunk & 15;
      *(f16x8*)&Vth[(((size_t)b * CH + h) * CDK + r) * CS + s0 + cb * 8] =
          *(const f16x8*)&sm.Ts[r][cb * 8];
    }
  } else {
    f16* O = (which == 0) ? Qh : Kh;
    const float qsc = (which == 0) ? rsqrtf((float)lens[b]) : 1.0f;
#pragma unroll
    for (int i = 0; i < 4; ++i) {
#pragma unroll
      for (int rr = 0; rr < 4; ++rr) {
        const int s = s0 + wr * 64 + i * 16 + quad * 4 + rr;
        const size_t base = (((size_t)b * CH + h) * CS + s) * CDK;
#pragma unroll
        for (int j = 0; j < 2; ++j)
          O[base + wc * 32 + j * 16 + lcol] = (f16)(acc[i][j][rr] * qsc);
      }
    }
  }
}

// ---------------------------------------------------------------------------
// Vsum[b,h,d] = sum_s V^T[b,h,d,s]  (for invalid-q-row uniform average)
// ---------------------------------------------------------------------------
__global__ __launch_bounds__(256) void vsum_kernel(const f16* __restrict__ Vth,
                                                   float* __restrict__ Vsum) {
  const int bh = blockIdx.x;  // 0..127
  const int t = threadIdx.x;
  const int r = t >> 2, c = t & 3;
  const f16* src = Vth + ((size_t)bh * CDK + r) * CS;
  float s = 0.f;
  for (int i = 0; i < CS; i += 32) {
    f16x8 v = *(const f16x8*)&src[i + c * 8];
#pragma unroll
    for (int j = 0; j < 8; ++j) s += (float)v[j];
  }
  s += __shfl_xor(s, 1);
  s += __shfl_xor(s, 2);
  if (c == 0) Vsum[(size_t)bh * CDK + r] = s;
}

// ---------------------------------------------------------------------------
// Attention (MFMA flash, no-max softmax; Q pre-scaled).
//   S = Q·K^T via MFMA (C-layout [q][k]); exp with k<n mask only;
//   P round-trips through wave-private LDS into A-frags; O = P·V via MFMA.
//   Tail k-tiles (kt*64 >= n) skipped entirely.
//   Invalid q rows (q >= n) -> output Vsum/1024 (uniform softmax over S).
// grid (16 q-tiles, 8 heads, 16 batch), block 256 = 4 waves x 16 q-rows.
// ---------------------------------------------------------------------------
__global__ __launch_bounds__(256) void attn_kernel(
    const f16* __restrict__ Qh, const f16* __restrict__ Kh,
    const f16* __restrict__ Vth, const int* __restrict__ lens,
    const float* __restrict__ Vsum, f16* __restrict__ Hbh) {
  const int qt = blockIdx.x, h = blockIdx.y, b = blockIdx.z;
  const int n = lens[b];
  const int nt = (n + 63) >> 6;
  const int t = threadIdx.x, w = t >> 6, lane = t & 63, quad = lane >> 4,
            lcol = lane & 15;

  __shared__ f16 Ks[64][72];       // [k][d]
  __shared__ f16 Vs[64][72];       // V^T: [d][k]
  __shared__ float Pt[4][16][68];  // wave-private P

  const size_t bh = ((size_t)b * CH + h) * CS;
  const size_t bhd = ((size_t)b * CH + h) * CDK;

  const int qrow = qt * 64 + w * 16 + lcol;  // A-frag q row for this lane
  const f16x8 qa0 = *(const f16x8*)&Qh[(bh + qrow) * CDK + quad * 8];
  const f16x8 qa1 = *(const f16x8*)&Qh[(bh + qrow) * CDK + 32 + quad * 8];

  f32x4 o[4];
#pragma unroll
  for (int dt = 0; dt < 4; ++dt) o[dt] = (f32x4){0.f, 0.f, 0.f, 0.f};
  float lp[4] = {0.f, 0.f, 0.f, 0.f};

  for (int kt = 0; kt < nt; ++kt) {
    __syncthreads();  // prior PV reads of Ks/Vs done
#pragma unroll
    for (int i = 0; i < 2; ++i) {
      const int c = t + 256 * i, r = c >> 3, sg = c & 7;
      *(f16x8*)&Ks[r][sg * 8] =
          *(const f16x8*)&Kh[(bh + kt * 64 + r) * CDK + sg * 8];
      *(f16x8*)&Vs[r][sg * 8] =
          *(const f16x8*)&Vth[(bhd + r) * CS + kt * 64 + sg * 8];
    }
    __syncthreads();

    // S tiles: s[ct] -> rows q = quad*4+rr (within wave's 16), cols k = ct*16+lcol
    f32x4 s[4];
#pragma unroll
    for (int ct = 0; ct < 4; ++ct) s[ct] = (f32x4){0.f, 0.f, 0.f, 0.f};
#pragma unroll
    for (int ct = 0; ct < 4; ++ct) {
      const f16x8 kb0 = *(const f16x8*)&Ks[ct * 16 + lcol][quad * 8];
      const f16x8 kb1 = *(const f16x8*)&Ks[ct * 16 + lcol][32 + quad * 8];
      s[ct] = mfma16(qa0, kb0, s[ct]);
      s[ct] = mfma16(qa1, kb1, s[ct]);
    }

    // exp + k-mask (no q mask: invalid rows overridden in epilogue; no scale:
    // Q pre-scaled; no max subtraction: |scores| = O(1))
#pragma unroll
    for (int ct = 0; ct < 4; ++ct) {
      const bool kvld = (kt * 64 + ct * 16 + lcol) < n;
#pragma unroll
      for (int r = 0; r < 4; ++r) {
        float p = __expf(s[ct][r]);
        p = kvld ? p : 0.f;
        lp[r] += p;
        Pt[w][quad * 4 + r][ct * 16 + lcol] = p;
      }
    }

    // P -> A-operand frags (wave-private LDS round-trip, barrier-free)
    f16x8 pa0, pa1;
    {
      const float* pr = &Pt[w][lcol][quad * 8];
      const float4 u0 = *(const float4*)pr;
      const float4 u1 = *(const float4*)(pr + 4);
      pa0[0] = (f16)u0.x; pa0[1] = (f16)u0.y; pa0[2] = (f16)u0.z; pa0[3] = (f16)u0.w;
      pa0[4] = (f16)u1.x; pa0[5] = (f16)u1.y; pa0[6] = (f16)u1.z; pa0[7] = (f16)u1.w;
      const float* pr2 = &Pt[w][lcol][32 + quad * 8];
      const float4 v0 = *(const float4*)pr2;
      const float4 v1 = *(const float4*)(pr2 + 4);
      pa1[0] = (f16)v0.x; pa1[1] = (f16)v0.y; pa1[2] = (f16)v0.z; pa1[3] = (f16)v0.w;
      pa1[4] = (f16)v1.x; pa1[5] = (f16)v1.y; pa1[6] = (f16)v1.z; pa1[7] = (f16)v1.w;
    }

#pragma unroll
    for (int dt = 0; dt < 4; ++dt) {
      const f16x8 vb0 = *(const f16x8*)&Vs[dt * 16 + lcol][quad * 8];
      const f16x8 vb1 = *(const f16x8*)&Vs[dt * 16 + lcol][32 + quad * 8];
      o[dt] = mfma16(pa0, vb0, o[dt]);
      o[dt] = mfma16(pa1, vb1, o[dt]);
    }
  }

  float invl[4];
#pragma unroll
  for (int r = 0; r < 4; ++r) {
    float v = lp[r];
    v += __shfl_xor(v, 1);
    v += __shfl_xor(v, 2);
    v += __shfl_xor(v, 4);
    v += __shfl_xor(v, 8);
    invl[r] = 1.0f / v;
  }

#pragma unroll
  for (int dt = 0; dt < 4; ++dt)
#pragma unroll
    for (int r = 0; r < 4; ++r) {
      const int srow = qt * 64 + w * 16 + quad * 4 + r;
      const int d = dt * 16 + lcol;
      const float val = (srow < n) ? o[dt][r] * invl[r]
                                   : Vsum[bhd + d] * (1.0f / 1024.0f);
      Hbh[((size_t)b * CS + srow) * (CH * CDK) + h * CDK + d] = (f16)val;
    }
}

// ---------------------------------------------------------------------------
// Output projection (MFMA): out[16384,512] = Hbh[16384,512] @ Wout[512,512]
// ---------------------------------------------------------------------------
__global__ __launch_bounds__(256) void outp_kernel(const f16* __restrict__ Hbh,
                                                   const f16* __restrict__ woutt,
                                                   float* __restrict__ out) {
  const int rt = blockIdx.x, ctile = blockIdx.y;
  const int row0 = rt * 128, col0 = ctile * 64;
  const f16* Wt = woutt + (size_t)col0 * CHID;
  const int t = threadIdx.x;
  const int w = t >> 6, lane = t & 63, quad = lane >> 4, lcol = lane & 15;
  const int wr = w >> 1, wc = w & 1;

  __shared__ f16 Hs[128][40];
  __shared__ f16 Ws[64][40];

  f32x4 acc[4][2];
#pragma unroll
  for (int i = 0; i < 4; ++i)
#pragma unroll
    for (int j = 0; j < 2; ++j) acc[i][j] = (f32x4){0.f, 0.f, 0.f, 0.f};

  for (int k0 = 0; k0 < CHID; k0 += 32) {
#pragma unroll
    for (int i = 0; i < 2; ++i) {
      const int c = t + 256 * i, r = c >> 2, sg = c & 3;
      *(f16x8*)&Hs[r][sg * 8] =
          *(const f16x8*)&Hbh[(size_t)(row0 + r) * CHID + k0 + sg * 8];
    }
    {
      const int r = t >> 2, sg = t & 3;
      *(f16x8*)&Ws[r][sg * 8] =
          *(const f16x8*)&Wt[(size_t)r * CHID + k0 + sg * 8];
    }
    __syncthreads();
    f16x8 af[4], bf[2];
#pragma unroll
    for (int i = 0; i < 4; ++i)
      af[i] = *(const f16x8*)&Hs[wr * 64 + i * 16 + lcol][quad * 8];
#pragma unroll
    for (int j = 0; j < 2; ++j)
      bf[j] = *(const f16x8*)&Ws[wc * 32 + j * 16 + lcol][quad * 8];
#pragma unroll
    for (int i = 0; i < 4; ++i)
#pragma unroll
      for (int j = 0; j < 2; ++j) acc[i][j] = mfma16(af[i], bf[j], acc[i][j]);
    __syncthreads();
  }

#pragma unroll
  for (int i = 0; i < 4; ++i) {
#pragma unroll
    for (int rr = 0; rr < 4; ++rr) {
      const size_t rg = row0 + wr * 64 + i * 16 + quad * 4 + rr;
#pragma unroll
      for (int j = 0; j < 2; ++j)
        out[rg * CHID + col0 + wc * 32 + j * 16 + lcol] = acc[i][j][rr];
    }
  }
}

// ---------------------------------------------------------------------------
extern "C" void kernel_launch(void* const* d_in, const int* in_sizes, int n_in,
                              void* d_out, int out_size, void* d_ws,
                              size_t ws_size, hipStream_t stream) {
  const float* x = (const float*)d_in[0];
  const int* mask = (const int*)d_in[1];
  const float* Wq = (const float*)d_in[2];
  const float* Wk = (const float*)d_in[3];
  const float* Wv = (const float*)d_in[4];
  const float* Wout = (const float*)d_in[5];
  float* out = (float*)d_out;

  char* ws = (char*)d_ws;
  int* lens = (int*)ws;
  size_t off = 1024;
  const size_t NX = (size_t)CB * CS * CHID;   // 8,388,608
  const size_t NW = (size_t)CH * CHID * CDK;  // 262,144 per weight
  f16* xh = (f16*)(ws + off);    off += NX * 2;
  f16* wtAll = (f16*)(ws + off); off += NW * 4 * 2;
  f16* Qh = (f16*)(ws + off);    off += NX * 2;
  f16* Kh = (f16*)(ws + off);    off += NX * 2;
  f16* Vth = (f16*)(ws + off);   off += NX * 2;
  f16* Hbh = (f16*)(ws + off);   off += NX * 2;
  float* Vsum = (float*)(ws + off); off += (size_t)CB * CH * CDK * 4;
  f16* woutt = wtAll + NW * 3;

  lengths_kernel<<<CB, 256, 0, stream>>>(mask, lens);
  cast_x_kernel<<<NX / 4 / 256, 256, 0, stream>>>((const float4*)x, (f16x4*)xh);
  cast_w_kernel<<<dim3(256, 4), 256, 0, stream>>>(Wq, Wk, Wv, Wout, wtAll);
  qkv_kernel<<<dim3(128, 24), 256, 0, stream>>>(xh, wtAll, lens, Qh, Kh, Vth);
  vsum_kernel<<<CB * CH, 256, 0, stream>>>(Vth, Vsum);
  attn_kernel<<<dim3(CS / 64, CH, CB), 256, 0, stream>>>(Qh, Kh, Vth, lens,
                                                         Vsum, Hbh);
  outp_kernel<<<dim3(128, 8), 256, 0, stream>>>(Hbh, woutt, out);
}

// Round 6
// 222.216 us; speedup vs baseline: 9.4796x; 1.1487x over previous
//
#include <hip/hip_runtime.h>
#include <math.h>

// QANetAttBlock: B=16, S=1024, HID=512, H=8, DK=64
constexpr int CB = 16;
constexpr int CS = 1024;
constexpr int CHID = 512;
constexpr int CH = 8;
constexpr int CDK = 64;

typedef _Float16 f16;
typedef __attribute__((ext_vector_type(8))) _Float16 f16x8;
typedef __attribute__((ext_vector_type(4))) _Float16 f16x4;
typedef __attribute__((ext_vector_type(4))) float f32x4;

__device__ inline f32x4 mfma16(f16x8 a, f16x8 b, f32x4 c) {
  return __builtin_amdgcn_mfma_f32_16x16x32_f16(a, b, c, 0, 0, 0);
}

// ---------------------------------------------------------------------------
// lengths: per-batch prefix-mask sum
// ---------------------------------------------------------------------------
__global__ __launch_bounds__(256) void lengths_kernel(const int* __restrict__ mask,
                                                      int* __restrict__ lens) {
  const int b = blockIdx.x, t = threadIdx.x;
  __shared__ int red[256];
  int s = 0;
  for (int i = t; i < CS; i += 256) s += mask[b * CS + i];
  red[t] = s;
  __syncthreads();
  for (int off = 128; off > 0; off >>= 1) {
    if (t < off) red[t] += red[t + off];
    __syncthreads();
  }
  if (t == 0) lens[b] = red[0];
}

// ---------------------------------------------------------------------------
// cast x (fp32 -> fp16)
// ---------------------------------------------------------------------------
__global__ __launch_bounds__(256) void cast_x_kernel(const float4* __restrict__ x,
                                                     f16x4* __restrict__ xh) {
  const int idx = blockIdx.x * 256 + threadIdx.x;
  const float4 v = x[idx];
  f16x4 o;
  o[0] = (f16)v.x; o[1] = (f16)v.y; o[2] = (f16)v.z; o[3] = (f16)v.w;
  xh[idx] = o;
}

// ---------------------------------------------------------------------------
// cast + transpose weights
// y in 0..2: W[y] [8][512][64] (h,k,n) -> [8][64][512] (h,n,k)
// y == 3:    Wout [512][512] (k,n)     -> [512][512] (n,k)
// ---------------------------------------------------------------------------
__global__ __launch_bounds__(256) void cast_w_kernel(const float* __restrict__ Wq,
                                                     const float* __restrict__ Wk,
                                                     const float* __restrict__ Wv,
                                                     const float* __restrict__ Wout,
                                                     f16* __restrict__ wtAll) {
  const int y = blockIdx.y;
  const int o0 = (blockIdx.x * 256 + threadIdx.x) * 4;
  f16* D = wtAll + (size_t)y * 262144;
  f16x4 d;
  if (y < 3) {
    const float* W = (y == 0) ? Wq : (y == 1) ? Wk : Wv;
    const int h = o0 >> 15, n = (o0 >> 9) & 63, k = o0 & 511;
    const size_t in = (size_t)h * 32768 + (size_t)k * 64 + n;
#pragma unroll
    for (int j = 0; j < 4; ++j) d[j] = (f16)W[in + (size_t)j * 64];
  } else {
    const int n = o0 >> 9, k = o0 & 511;
#pragma unroll
    for (int j = 0; j < 4; ++j) d[j] = (f16)Wout[(size_t)(k + j) * 512 + n];
  }
  *(f16x4*)&D[o0] = d;
}

// ---------------------------------------------------------------------------
// Fused QKV projection: one 128x128-tile GEMM vs Wcat[512, 1536].
// grid (128 row-tiles, 12 col-tiles); ct -> which = ct>>2, head pair = ct&3.
// Per block: 4 waves (2x2), each 64x64 -> 16 MFMA / 32-k step.
// Q pre-scaled by 1/sqrt(n[b]); V transposed through LDS -> V^T [B,H,64,S].
// ---------------------------------------------------------------------------
__global__ __launch_bounds__(256) void qkvf_kernel(
    const f16* __restrict__ xh, const f16* __restrict__ wtAll,
    const int* __restrict__ lens, f16* __restrict__ Qh, f16* __restrict__ Kh,
    f16* __restrict__ Vth) {
  const int rt = blockIdx.x, ct = blockIdx.y;
  const int which = ct >> 2, hp = ct & 3;
  const f16* Wt = wtAll + (size_t)which * 262144 + (size_t)hp * 65536;  // [128n][512k]
  const int row0 = rt * 128;
  const int b = row0 >> 10, s0 = row0 & 1023;
  const int h0 = hp * 2;
  const int t = threadIdx.x;
  const int w = t >> 6, lane = t & 63, quad = lane >> 4, lcol = lane & 15;
  const int wr = w >> 1, wc = w & 1;

  __shared__ union SM {
    struct { f16 Xs[128][40]; f16 Ws[128][40]; } a;
    f16 Ts[128][136];  // V-transpose staging (epilogue only)
  } sm;

  f32x4 acc[4][4];
#pragma unroll
  for (int i = 0; i < 4; ++i)
#pragma unroll
    for (int j = 0; j < 4; ++j) acc[i][j] = (f32x4){0.f, 0.f, 0.f, 0.f};

  for (int k0 = 0; k0 < CHID; k0 += 32) {
#pragma unroll
    for (int i = 0; i < 2; ++i) {
      const int c = t + 256 * i, r = c >> 2, sg = c & 3;
      *(f16x8*)&sm.a.Xs[r][sg * 8] =
          *(const f16x8*)&xh[(size_t)(row0 + r) * CHID + k0 + sg * 8];
      *(f16x8*)&sm.a.Ws[r][sg * 8] =
          *(const f16x8*)&Wt[(size_t)r * CHID + k0 + sg * 8];
    }
    __syncthreads();
    f16x8 af[4], bf[4];
#pragma unroll
    for (int i = 0; i < 4; ++i)
      af[i] = *(const f16x8*)&sm.a.Xs[wr * 64 + i * 16 + lcol][quad * 8];
#pragma unroll
    for (int j = 0; j < 4; ++j)
      bf[j] = *(const f16x8*)&sm.a.Ws[wc * 64 + j * 16 + lcol][quad * 8];
#pragma unroll
    for (int i = 0; i < 4; ++i)
#pragma unroll
      for (int j = 0; j < 4; ++j) acc[i][j] = mfma16(af[i], bf[j], acc[i][j]);
    __syncthreads();
  }

  if (which == 2) {
    // transpose 128s x 128n tile through LDS, store V^T coalesced
#pragma unroll
    for (int i = 0; i < 4; ++i)
#pragma unroll
      for (int j = 0; j < 4; ++j)
#pragma unroll
        for (int rr = 0; rr < 4; ++rr)
          sm.Ts[wc * 64 + j * 16 + lcol][wr * 64 + i * 16 + quad * 4 + rr] =
              (f16)acc[i][j][rr];
    __syncthreads();
    const int nl = t >> 1, half = t & 1;
    const int h = h0 + (nl >> 6), d = nl & 63;
    f16* dst = &Vth[(((size_t)b * CH + h) * CDK + d) * CS + s0 + half * 64];
#pragma unroll
    for (int c8 = 0; c8 < 8; ++c8)
      *(f16x8*)&dst[c8 * 8] = *(const f16x8*)&sm.Ts[nl][half * 64 + c8 * 8];
  } else {
    f16* O = (which == 0) ? Qh : Kh;
    const float qsc = (which == 0) ? rsqrtf((float)lens[b]) : 1.0f;
    const int h = h0 + wc;
#pragma unroll
    for (int i = 0; i < 4; ++i) {
#pragma unroll
      for (int rr = 0; rr < 4; ++rr) {
        const int s = s0 + wr * 64 + i * 16 + quad * 4 + rr;
        const size_t base = (((size_t)b * CH + h) * CS + s) * CDK;
#pragma unroll
        for (int j = 0; j < 4; ++j)
          O[base + j * 16 + lcol] = (f16)(acc[i][j][rr] * qsc);
      }
    }
  }
}

// ---------------------------------------------------------------------------
// Vsum[b,h,d] = sum_s V^T[b,h,d,s]  (for invalid-q-row uniform average)
// ---------------------------------------------------------------------------
__global__ __launch_bounds__(256) void vsum_kernel(const f16* __restrict__ Vth,
                                                   float* __restrict__ Vsum) {
  const int bh = blockIdx.x;  // 0..127
  const int t = threadIdx.x;
  const int r = t >> 2, c = t & 3;
  const f16* src = Vth + ((size_t)bh * CDK + r) * CS;
  float s = 0.f;
  for (int i = 0; i < CS; i += 32) {
    f16x8 v = *(const f16x8*)&src[i + c * 8];
#pragma unroll
    for (int j = 0; j < 8; ++j) s += (float)v[j];
  }
  s += __shfl_xor(s, 1);
  s += __shfl_xor(s, 2);
  if (c == 0) Vsum[(size_t)bh * CDK + r] = s;
}

// ---------------------------------------------------------------------------
// Attention (MFMA flash, no-max softmax; Q pre-scaled).
// q-tile 128/block, 4 waves x 32 q-rows (2 A-frag row sets).
//   S = Q·K^T (C-layout); exp w/ k<n mask; P(f16) via wave-private LDS
//   round-trip into A-frags; O = P·V. Tail k-tiles skipped; q>=n rows ->
//   Vsum/1024.
// grid (8 q-tiles, 8 heads, 16 batch), block 256.
// ---------------------------------------------------------------------------
__global__ __launch_bounds__(256) void attn_kernel(
    const f16* __restrict__ Qh, const f16* __restrict__ Kh,
    const f16* __restrict__ Vth, const int* __restrict__ lens,
    const float* __restrict__ Vsum, f16* __restrict__ Hbh) {
  const int qt = blockIdx.x, h = blockIdx.y, b = blockIdx.z;
  const int n = lens[b];
  const int nt = (n + 63) >> 6;
  const int t = threadIdx.x, w = t >> 6, lane = t & 63, quad = lane >> 4,
            lcol = lane & 15;

  __shared__ f16 Ks[64][72];      // [k][d]
  __shared__ f16 Vs[64][72];      // V^T: [d][k]
  __shared__ f16 Pt[4][32][72];   // wave-private P (f16)

  const size_t bh = ((size_t)b * CH + h) * CS;
  const size_t bhd = ((size_t)b * CH + h) * CDK;

  const int qbase = qt * 128 + w * 32;
  f16x8 qa[2][2];
#pragma unroll
  for (int set = 0; set < 2; ++set) {
    const size_t qr = bh + qbase + set * 16 + lcol;
    qa[set][0] = *(const f16x8*)&Qh[qr * CDK + quad * 8];
    qa[set][1] = *(const f16x8*)&Qh[qr * CDK + 32 + quad * 8];
  }

  f32x4 o[2][4];
#pragma unroll
  for (int set = 0; set < 2; ++set)
#pragma unroll
    for (int dt = 0; dt < 4; ++dt) o[set][dt] = (f32x4){0.f, 0.f, 0.f, 0.f};
  float lp[2][4] = {{0.f, 0.f, 0.f, 0.f}, {0.f, 0.f, 0.f, 0.f}};

  for (int kt = 0; kt < nt; ++kt) {
    __syncthreads();  // prior PV reads of Ks/Vs done
#pragma unroll
    for (int i = 0; i < 2; ++i) {
      const int c = t + 256 * i, r = c >> 3, sg = c & 7;
      *(f16x8*)&Ks[r][sg * 8] =
          *(const f16x8*)&Kh[(bh + kt * 64 + r) * CDK + sg * 8];
      *(f16x8*)&Vs[r][sg * 8] =
          *(const f16x8*)&Vth[(bhd + r) * CS + kt * 64 + sg * 8];
    }
    __syncthreads();

    // QK + exp, set-serial (caps VGPR pressure; kb reloaded per set)
#pragma unroll
    for (int set = 0; set < 2; ++set) {
      f32x4 st[4];
#pragma unroll
      for (int ct = 0; ct < 4; ++ct) {
        const f16x8 kb0 = *(const f16x8*)&Ks[ct * 16 + lcol][quad * 8];
        const f16x8 kb1 = *(const f16x8*)&Ks[ct * 16 + lcol][32 + quad * 8];
        st[ct] = mfma16(qa[set][0], kb0, (f32x4){0.f, 0.f, 0.f, 0.f});
        st[ct] = mfma16(qa[set][1], kb1, st[ct]);
      }
#pragma unroll
      for (int ct = 0; ct < 4; ++ct) {
        const bool kvld = (kt * 64 + ct * 16 + lcol) < n;
#pragma unroll
        for (int r = 0; r < 4; ++r) {
          float p = __expf(st[ct][r]);
          p = kvld ? p : 0.f;
          lp[set][r] += p;
          Pt[w][set * 16 + quad * 4 + r][ct * 16 + lcol] = (f16)p;
        }
      }
    }

    // P -> A-frags (wave-private, barrier-free)
    f16x8 pa[2][2];
#pragma unroll
    for (int set = 0; set < 2; ++set) {
      pa[set][0] = *(const f16x8*)&Pt[w][set * 16 + lcol][quad * 8];
      pa[set][1] = *(const f16x8*)&Pt[w][set * 16 + lcol][32 + quad * 8];
    }

#pragma unroll
    for (int dt = 0; dt < 4; ++dt) {
      const f16x8 vb0 = *(const f16x8*)&Vs[dt * 16 + lcol][quad * 8];
      const f16x8 vb1 = *(const f16x8*)&Vs[dt * 16 + lcol][32 + quad * 8];
#pragma unroll
      for (int set = 0; set < 2; ++set) {
        o[set][dt] = mfma16(pa[set][0], vb0, o[set][dt]);
        o[set][dt] = mfma16(pa[set][1], vb1, o[set][dt]);
      }
    }
  }

  float invl[2][4];
#pragma unroll
  for (int set = 0; set < 2; ++set)
#pragma unroll
    for (int r = 0; r < 4; ++r) {
      float v = lp[set][r];
      v += __shfl_xor(v, 1);
      v += __shfl_xor(v, 2);
      v += __shfl_xor(v, 4);
      v += __shfl_xor(v, 8);
      invl[set][r] = 1.0f / v;
    }

#pragma unroll
  for (int set = 0; set < 2; ++set)
#pragma unroll
    for (int dt = 0; dt < 4; ++dt)
#pragma unroll
      for (int r = 0; r < 4; ++r) {
        const int srow = qbase + set * 16 + quad * 4 + r;
        const int d = dt * 16 + lcol;
        const float val = (srow < n) ? o[set][dt][r] * invl[set][r]
                                     : Vsum[bhd + d] * (1.0f / 1024.0f);
        Hbh[((size_t)b * CS + srow) * (CH * CDK) + h * CDK + d] = (f16)val;
      }
}

// ---------------------------------------------------------------------------
// Output projection: out[16384,512] = Hbh @ Wout, 128x128 tiles.
// grid (128 row-tiles, 4 col-tiles), block 256 (4 waves, 2x2).
// ---------------------------------------------------------------------------
__global__ __launch_bounds__(256) void outp_kernel(const f16* __restrict__ Hbh,
                                                   const f16* __restrict__ woutt,
                                                   float* __restrict__ out) {
  const int rt = blockIdx.x, ctile = blockIdx.y;
  const int row0 = rt * 128, col0 = ctile * 128;
  const f16* Wt = woutt + (size_t)col0 * CHID;  // [128n][512k]
  const int t = threadIdx.x;
  const int w = t >> 6, lane = t & 63, quad = lane >> 4, lcol = lane & 15;
  const int wr = w >> 1, wc = w & 1;

  __shared__ f16 Hs[128][40];
  __shared__ f16 Ws[128][40];

  f32x4 acc[4][4];
#pragma unroll
  for (int i = 0; i < 4; ++i)
#pragma unroll
    for (int j = 0; j < 4; ++j) acc[i][j] = (f32x4){0.f, 0.f, 0.f, 0.f};

  for (int k0 = 0; k0 < CHID; k0 += 32) {
#pragma unroll
    for (int i = 0; i < 2; ++i) {
      const int c = t + 256 * i, r = c >> 2, sg = c & 3;
      *(f16x8*)&Hs[r][sg * 8] =
          *(const f16x8*)&Hbh[(size_t)(row0 + r) * CHID + k0 + sg * 8];
      *(f16x8*)&Ws[r][sg * 8] =
          *(const f16x8*)&Wt[(size_t)r * CHID + k0 + sg * 8];
    }
    __syncthreads();
    f16x8 af[4], bf[4];
#pragma unroll
    for (int i = 0; i < 4; ++i)
      af[i] = *(const f16x8*)&Hs[wr * 64 + i * 16 + lcol][quad * 8];
#pragma unroll
    for (int j = 0; j < 4; ++j)
      bf[j] = *(const f16x8*)&Ws[wc * 64 + j * 16 + lcol][quad * 8];
#pragma unroll
    for (int i = 0; i < 4; ++i)
#pragma unroll
      for (int j = 0; j < 4; ++j) acc[i][j] = mfma16(af[i], bf[j], acc[i][j]);
    __syncthreads();
  }

#pragma unroll
  for (int i = 0; i < 4; ++i) {
#pragma unroll
    for (int rr = 0; rr < 4; ++rr) {
      const size_t rg = row0 + wr * 64 + i * 16 + quad * 4 + rr;
#pragma unroll
      for (int j = 0; j < 4; ++j)
        out[rg * CHID + col0 + wc * 64 + j * 16 + lcol] = acc[i][j][rr];
    }
  }
}

// ---------------------------------------------------------------------------
extern "C" void kernel_launch(void* const* d_in, const int* in_sizes, int n_in,
                              void* d_out, int out_size, void* d_ws,
                              size_t ws_size, hipStream_t stream) {
  const float* x = (const float*)d_in[0];
  const int* mask = (const int*)d_in[1];
  const float* Wq = (const float*)d_in[2];
  const float* Wk = (const float*)d_in[3];
  const float* Wv = (const float*)d_in[4];
  const float* Wout = (const float*)d_in[5];
  float* out = (float*)d_out;

  char* ws = (char*)d_ws;
  int* lens = (int*)ws;
  size_t off = 1024;
  const size_t NX = (size_t)CB * CS * CHID;   // 8,388,608
  const size_t NW = (size_t)CH * CHID * CDK;  // 262,144 per weight
  f16* xh = (f16*)(ws + off);    off += NX * 2;
  f16* wtAll = (f16*)(ws + off); off += NW * 4 * 2;
  f16* Qh = (f16*)(ws + off);    off += NX * 2;
  f16* Kh = (f16*)(ws + off);    off += NX * 2;
  f16* Vth = (f16*)(ws + off);   off += NX * 2;
  f16* Hbh = (f16*)(ws + off);   off += NX * 2;
  float* Vsum = (float*)(ws + off); off += (size_t)CB * CH * CDK * 4;
  f16* woutt = wtAll + NW * 3;

  lengths_kernel<<<CB, 256, 0, stream>>>(mask, lens);
  cast_x_kernel<<<NX / 4 / 256, 256, 0, stream>>>((const float4*)x, (f16x4*)xh);
  cast_w_kernel<<<dim3(256, 4), 256, 0, stream>>>(Wq, Wk, Wv, Wout, wtAll);
  qkvf_kernel<<<dim3(128, 12), 256, 0, stream>>>(xh, wtAll, lens, Qh, Kh, Vth);
  vsum_kernel<<<CB * CH, 256, 0, stream>>>(Vth, Vsum);
  attn_kernel<<<dim3(CS / 128, CH, CB), 256, 0, stream>>>(Qh, Kh, Vth, lens,
                                                          Vsum, Hbh);
  outp_kernel<<<dim3(128, 4), 256, 0, stream>>>(Hbh, woutt, out);
}

// Round 7
// 213.531 us; speedup vs baseline: 9.8652x; 1.0407x over previous
//
#include <hip/hip_runtime.h>
#include <math.h>

// QANetAttBlock: B=16, S=1024, HID=512, H=8, DK=64
constexpr int CB = 16;
constexpr int CS = 1024;
constexpr int CHID = 512;
constexpr int CH = 8;
constexpr int CDK = 64;

typedef _Float16 f16;
typedef __attribute__((ext_vector_type(8))) _Float16 f16x8;
typedef __attribute__((ext_vector_type(4))) _Float16 f16x4;
typedef __attribute__((ext_vector_type(4))) float f32x4;

__device__ inline f32x4 mfma16(f16x8 a, f16x8 b, f32x4 c) {
  return __builtin_amdgcn_mfma_f32_16x16x32_f16(a, b, c, 0, 0, 0);
}

// ---------------------------------------------------------------------------
// lengths: per-batch prefix-mask sum; also zero-inits Vsum (ws is poisoned).
// Runs first on the stream, so Vsum is zero before qkvf's atomics.
// ---------------------------------------------------------------------------
__global__ __launch_bounds__(256) void lengths_kernel(const int* __restrict__ mask,
                                                      int* __restrict__ lens,
                                                      float* __restrict__ Vsum) {
  const int b = blockIdx.x, t = threadIdx.x;
  const int g = b * 256 + t;  // 0..4095
  Vsum[g * 2] = 0.f;
  Vsum[g * 2 + 1] = 0.f;
  __shared__ int red[256];
  int s = 0;
  for (int i = t; i < CS; i += 256) s += mask[b * CS + i];
  red[t] = s;
  __syncthreads();
  for (int off = 128; off > 0; off >>= 1) {
    if (t < off) red[t] += red[t + off];
    __syncthreads();
  }
  if (t == 0) lens[b] = red[0];
}

// ---------------------------------------------------------------------------
// cast x (fp32 -> fp16)
// ---------------------------------------------------------------------------
__global__ __launch_bounds__(256) void cast_x_kernel(const float4* __restrict__ x,
                                                     f16x4* __restrict__ xh) {
  const int idx = blockIdx.x * 256 + threadIdx.x;
  const float4 v = x[idx];
  f16x4 o;
  o[0] = (f16)v.x; o[1] = (f16)v.y; o[2] = (f16)v.z; o[3] = (f16)v.w;
  xh[idx] = o;
}

// ---------------------------------------------------------------------------
// cast + transpose weights via LDS (coalesced fp32 reads).
// Panels of [512 k][64 n] fp32 -> [64 n][512 k] f16.
//   blockIdx.y < 24: QKV, which = y>>3, h = y&7
//   blockIdx.y >= 24: Wout col-chunk c = y-24 (cols c*64..c*64+63)
// blockIdx.x = k-block (64 rows of k). 256 threads.
// ---------------------------------------------------------------------------
__global__ __launch_bounds__(256) void cast_w_kernel(const float* __restrict__ Wq,
                                                     const float* __restrict__ Wk,
                                                     const float* __restrict__ Wv,
                                                     const float* __restrict__ Wout,
                                                     f16* __restrict__ wtAll) {
  const int y = blockIdx.y, kb = blockIdx.x, t = threadIdx.x;
  const int k0 = kb * 64;
  const float* src;
  int ldsrc;
  f16* dst;
  if (y < 24) {
    const int which = y >> 3, h = y & 7;
    const float* W = (which == 0) ? Wq : (which == 1) ? Wk : Wv;
    src = W + (size_t)h * 32768 + (size_t)k0 * 64;
    ldsrc = 64;
    dst = wtAll + (size_t)which * 262144 + (size_t)h * 32768;
  } else {
    const int c = y - 24;
    src = Wout + (size_t)k0 * 512 + c * 64;
    ldsrc = 512;
    dst = wtAll + (size_t)3 * 262144 + (size_t)c * 64 * 512;
  }

  __shared__ float Ts[64][68];
  {
    const int kr = t >> 4, cg = (t & 15) * 4;
#pragma unroll
    for (int rr = 0; rr < 4; ++rr) {
      const float4 v = *(const float4*)&src[(size_t)(rr * 16 + kr) * ldsrc + cg];
      Ts[rr * 16 + kr][cg] = v.x;
      Ts[rr * 16 + kr][cg + 1] = v.y;
      Ts[rr * 16 + kr][cg + 2] = v.z;
      Ts[rr * 16 + kr][cg + 3] = v.w;
    }
  }
  __syncthreads();
  {
    const int n = t >> 2, seg = t & 3;
    f16x8 a, b;
#pragma unroll
    for (int j = 0; j < 8; ++j) {
      a[j] = (f16)Ts[seg * 16 + j][n];
      b[j] = (f16)Ts[seg * 16 + 8 + j][n];
    }
    f16* d = &dst[(size_t)n * 512 + k0 + seg * 16];
    *(f16x8*)d = a;
    *(f16x8*)(d + 8) = b;
  }
}

// ---------------------------------------------------------------------------
// Fused QKV projection: 128x128-tile GEMM vs Wcat[512, 1536], reg-prefetch.
// grid (128 row-tiles, 12 col-tiles); which = ct>>2, head pair = ct&3.
// Q pre-scaled by 1/sqrt(n[b]); V transposed through LDS -> V^T [B,H,64,S];
// V fp32 column sums atomically accumulated into Vsum.
// ---------------------------------------------------------------------------
__global__ __launch_bounds__(256) void qkvf_kernel(
    const f16* __restrict__ xh, const f16* __restrict__ wtAll,
    const int* __restrict__ lens, f16* __restrict__ Qh, f16* __restrict__ Kh,
    f16* __restrict__ Vth, float* __restrict__ Vsum) {
  const int rt = blockIdx.x, ct = blockIdx.y;
  const int which = ct >> 2, hp = ct & 3;
  const f16* Wt = wtAll + (size_t)which * 262144 + (size_t)hp * 65536;
  const int row0 = rt * 128;
  const int b = row0 >> 10, s0 = row0 & 1023;
  const int h0 = hp * 2;
  const int t = threadIdx.x;
  const int w = t >> 6, lane = t & 63, quad = lane >> 4, lcol = lane & 15;
  const int wr = w >> 1, wc = w & 1;

  __shared__ union SM {
    struct { f16 Xs[128][40]; f16 Ws[128][40]; } a;
    f16 Ts[128][136];  // V-transpose staging (epilogue only)
  } sm;

  f32x4 acc[4][4];
#pragma unroll
  for (int i = 0; i < 4; ++i)
#pragma unroll
    for (int j = 0; j < 4; ++j) acc[i][j] = (f32x4){0.f, 0.f, 0.f, 0.f};

  // register prefetch of tile k0=0
  f16x8 px[2], pw[2];
#pragma unroll
  for (int i = 0; i < 2; ++i) {
    const int c = t + 256 * i, r = c >> 2, sg = c & 3;
    px[i] = *(const f16x8*)&xh[(size_t)(row0 + r) * CHID + sg * 8];
    pw[i] = *(const f16x8*)&Wt[(size_t)r * CHID + sg * 8];
  }

  for (int k0 = 0; k0 < CHID; k0 += 32) {
    __syncthreads();  // prior iter's LDS reads done
#pragma unroll
    for (int i = 0; i < 2; ++i) {
      const int c = t + 256 * i, r = c >> 2, sg = c & 3;
      *(f16x8*)&sm.a.Xs[r][sg * 8] = px[i];
      *(f16x8*)&sm.a.Ws[r][sg * 8] = pw[i];
    }
    __syncthreads();
    const int kn = (k0 + 32 < CHID) ? k0 + 32 : k0;
#pragma unroll
    for (int i = 0; i < 2; ++i) {
      const int c = t + 256 * i, r = c >> 2, sg = c & 3;
      px[i] = *(const f16x8*)&xh[(size_t)(row0 + r) * CHID + kn + sg * 8];
      pw[i] = *(const f16x8*)&Wt[(size_t)r * CHID + kn + sg * 8];
    }
    f16x8 af[4], bf[4];
#pragma unroll
    for (int i = 0; i < 4; ++i)
      af[i] = *(const f16x8*)&sm.a.Xs[wr * 64 + i * 16 + lcol][quad * 8];
#pragma unroll
    for (int j = 0; j < 4; ++j)
      bf[j] = *(const f16x8*)&sm.a.Ws[wc * 64 + j * 16 + lcol][quad * 8];
#pragma unroll
    for (int i = 0; i < 4; ++i)
#pragma unroll
      for (int j = 0; j < 4; ++j) acc[i][j] = mfma16(af[i], bf[j], acc[i][j]);
  }

  if (which == 2) {
    // fp32 column sums -> Vsum (quad-reduced, one atomic per 4 lanes)
#pragma unroll
    for (int j = 0; j < 4; ++j) {
      float ps = 0.f;
#pragma unroll
      for (int i = 0; i < 4; ++i)
#pragma unroll
        for (int rr = 0; rr < 4; ++rr) ps += acc[i][j][rr];
      ps += __shfl_xor(ps, 16);
      ps += __shfl_xor(ps, 32);
      if (quad == 0) {
        const int d128 = wc * 64 + j * 16 + lcol;
        const int h = h0 + (d128 >> 6), d = d128 & 63;
        atomicAdd(&Vsum[((size_t)b * CH + h) * CDK + d], ps);
      }
    }
    // transpose 128s x 128n tile through LDS, store V^T coalesced
    __syncthreads();  // last k-iter LDS reads done before union reuse
#pragma unroll
    for (int i = 0; i < 4; ++i)
#pragma unroll
      for (int j = 0; j < 4; ++j)
#pragma unroll
        for (int rr = 0; rr < 4; ++rr)
          sm.Ts[wc * 64 + j * 16 + lcol][wr * 64 + i * 16 + quad * 4 + rr] =
              (f16)acc[i][j][rr];
    __syncthreads();
    const int nl = t >> 1, half = t & 1;
    const int h = h0 + (nl >> 6), d = nl & 63;
    f16* dst = &Vth[(((size_t)b * CH + h) * CDK + d) * CS + s0 + half * 64];
#pragma unroll
    for (int c8 = 0; c8 < 8; ++c8)
      *(f16x8*)&dst[c8 * 8] = *(const f16x8*)&sm.Ts[nl][half * 64 + c8 * 8];
  } else {
    f16* O = (which == 0) ? Qh : Kh;
    const float qsc = (which == 0) ? rsqrtf((float)lens[b]) : 1.0f;
    const int h = h0 + wc;
#pragma unroll
    for (int i = 0; i < 4; ++i) {
#pragma unroll
      for (int rr = 0; rr < 4; ++rr) {
        const int s = s0 + wr * 64 + i * 16 + quad * 4 + rr;
        const size_t base = (((size_t)b * CH + h) * CS + s) * CDK;
#pragma unroll
        for (int j = 0; j < 4; ++j)
          O[base + j * 16 + lcol] = (f16)(acc[i][j][rr] * qsc);
      }
    }
  }
}

// ---------------------------------------------------------------------------
// Attention (MFMA flash, no-max softmax; Q pre-scaled; reg-prefetch K/V).
// q-tile 128/block, 4 waves x 32 q-rows. Tail k-tiles skipped; q>=n rows ->
// Vsum/1024. grid (8 q-tiles, 8 heads, 16 batch), block 256.
// ---------------------------------------------------------------------------
__global__ __launch_bounds__(256) void attn_kernel(
    const f16* __restrict__ Qh, const f16* __restrict__ Kh,
    const f16* __restrict__ Vth, const int* __restrict__ lens,
    const float* __restrict__ Vsum, f16* __restrict__ Hbh) {
  const int qt = blockIdx.x, h = blockIdx.y, b = blockIdx.z;
  const int n = lens[b];
  const int nt = (n + 63) >> 6;
  const int t = threadIdx.x, w = t >> 6, lane = t & 63, quad = lane >> 4,
            lcol = lane & 15;

  __shared__ f16 Ks[64][72];     // [k][d]
  __shared__ f16 Vs[64][72];     // V^T: [d][k]
  __shared__ f16 Pt[4][32][72];  // wave-private P (f16)

  const size_t bh = ((size_t)b * CH + h) * CS;
  const size_t bhd = ((size_t)b * CH + h) * CDK;

  const int qbase = qt * 128 + w * 32;
  f16x8 qa[2][2];
#pragma unroll
  for (int set = 0; set < 2; ++set) {
    const size_t qr = bh + qbase + set * 16 + lcol;
    qa[set][0] = *(const f16x8*)&Qh[qr * CDK + quad * 8];
    qa[set][1] = *(const f16x8*)&Qh[qr * CDK + 32 + quad * 8];
  }

  f32x4 o[2][4];
#pragma unroll
  for (int set = 0; set < 2; ++set)
#pragma unroll
    for (int dt = 0; dt < 4; ++dt) o[set][dt] = (f32x4){0.f, 0.f, 0.f, 0.f};
  float lp[2][4] = {{0.f, 0.f, 0.f, 0.f}, {0.f, 0.f, 0.f, 0.f}};

  // register prefetch of k-tile 0
  f16x8 pk[2], pv[2];
#pragma unroll
  for (int i = 0; i < 2; ++i) {
    const int c = t + 256 * i, r = c >> 3, sg = c & 7;
    pk[i] = *(const f16x8*)&Kh[(bh + r) * CDK + sg * 8];
    pv[i] = *(const f16x8*)&Vth[(bhd + r) * CS + sg * 8];
  }

  for (int kt = 0; kt < nt; ++kt) {
    __syncthreads();  // prior iter's Ks/Vs reads done
#pragma unroll
    for (int i = 0; i < 2; ++i) {
      const int c = t + 256 * i, r = c >> 3, sg = c & 7;
      *(f16x8*)&Ks[r][sg * 8] = pk[i];
      *(f16x8*)&Vs[r][sg * 8] = pv[i];
    }
    __syncthreads();
    const int ktn = (kt + 1 < nt) ? kt + 1 : kt;
#pragma unroll
    for (int i = 0; i < 2; ++i) {
      const int c = t + 256 * i, r = c >> 3, sg = c & 7;
      pk[i] = *(const f16x8*)&Kh[(bh + ktn * 64 + r) * CDK + sg * 8];
      pv[i] = *(const f16x8*)&Vth[(bhd + r) * CS + ktn * 64 + sg * 8];
    }

    // QK + exp, set-serial
#pragma unroll
    for (int set = 0; set < 2; ++set) {
      f32x4 st[4];
#pragma unroll
      for (int ct = 0; ct < 4; ++ct) {
        const f16x8 kb0 = *(const f16x8*)&Ks[ct * 16 + lcol][quad * 8];
        const f16x8 kb1 = *(const f16x8*)&Ks[ct * 16 + lcol][32 + quad * 8];
        st[ct] = mfma16(qa[set][0], kb0, (f32x4){0.f, 0.f, 0.f, 0.f});
        st[ct] = mfma16(qa[set][1], kb1, st[ct]);
      }
#pragma unroll
      for (int ct = 0; ct < 4; ++ct) {
        const bool kvld = (kt * 64 + ct * 16 + lcol) < n;
#pragma unroll
        for (int r = 0; r < 4; ++r) {
          float p = __expf(st[ct][r]);
          p = kvld ? p : 0.f;
          lp[set][r] += p;
          Pt[w][set * 16 + quad * 4 + r][ct * 16 + lcol] = (f16)p;
        }
      }
    }

    // P -> A-frags (wave-private, barrier-free)
    f16x8 pa[2][2];
#pragma unroll
    for (int set = 0; set < 2; ++set) {
      pa[set][0] = *(const f16x8*)&Pt[w][set * 16 + lcol][quad * 8];
      pa[set][1] = *(const f16x8*)&Pt[w][set * 16 + lcol][32 + quad * 8];
    }

#pragma unroll
    for (int dt = 0; dt < 4; ++dt) {
      const f16x8 vb0 = *(const f16x8*)&Vs[dt * 16 + lcol][quad * 8];
      const f16x8 vb1 = *(const f16x8*)&Vs[dt * 16 + lcol][32 + quad * 8];
#pragma unroll
      for (int set = 0; set < 2; ++set) {
        o[set][dt] = mfma16(pa[set][0], vb0, o[set][dt]);
        o[set][dt] = mfma16(pa[set][1], vb1, o[set][dt]);
      }
    }
  }

  float invl[2][4];
#pragma unroll
  for (int set = 0; set < 2; ++set)
#pragma unroll
    for (int r = 0; r < 4; ++r) {
      float v = lp[set][r];
      v += __shfl_xor(v, 1);
      v += __shfl_xor(v, 2);
      v += __shfl_xor(v, 4);
      v += __shfl_xor(v, 8);
      invl[set][r] = 1.0f / v;
    }

#pragma unroll
  for (int set = 0; set < 2; ++set)
#pragma unroll
    for (int dt = 0; dt < 4; ++dt)
#pragma unroll
      for (int r = 0; r < 4; ++r) {
        const int srow = qbase + set * 16 + quad * 4 + r;
        const int d = dt * 16 + lcol;
        const float val = (srow < n) ? o[set][dt][r] * invl[set][r]
                                     : Vsum[bhd + d] * (1.0f / 1024.0f);
        Hbh[((size_t)b * CS + srow) * (CH * CDK) + h * CDK + d] = (f16)val;
      }
}

// ---------------------------------------------------------------------------
// Output projection: out[16384,512] = Hbh @ Wout, 128x128 tiles, reg-prefetch.
// grid (128 row-tiles, 4 col-tiles), block 256 (4 waves, 2x2).
// ---------------------------------------------------------------------------
__global__ __launch_bounds__(256) void outp_kernel(const f16* __restrict__ Hbh,
                                                   const f16* __restrict__ woutt,
                                                   float* __restrict__ out) {
  const int rt = blockIdx.x, ctile = blockIdx.y;
  const int row0 = rt * 128, col0 = ctile * 128;
  const f16* Wt = woutt + (size_t)col0 * CHID;
  const int t = threadIdx.x;
  const int w = t >> 6, lane = t & 63, quad = lane >> 4, lcol = lane & 15;
  const int wr = w >> 1, wc = w & 1;

  __shared__ f16 Hs[128][40];
  __shared__ f16 Ws[128][40];

  f32x4 acc[4][4];
#pragma unroll
  for (int i = 0; i < 4; ++i)
#pragma unroll
    for (int j = 0; j < 4; ++j) acc[i][j] = (f32x4){0.f, 0.f, 0.f, 0.f};

  f16x8 ph[2], pw[2];
#pragma unroll
  for (int i = 0; i < 2; ++i) {
    const int c = t + 256 * i, r = c >> 2, sg = c & 3;
    ph[i] = *(const f16x8*)&Hbh[(size_t)(row0 + r) * CHID + sg * 8];
    pw[i] = *(const f16x8*)&Wt[(size_t)r * CHID + sg * 8];
  }

  for (int k0 = 0; k0 < CHID; k0 += 32) {
    __syncthreads();
#pragma unroll
    for (int i = 0; i < 2; ++i) {
      const int c = t + 256 * i, r = c >> 2, sg = c & 3;
      *(f16x8*)&Hs[r][sg * 8] = ph[i];
      *(f16x8*)&Ws[r][sg * 8] = pw[i];
    }
    __syncthreads();
    const int kn = (k0 + 32 < CHID) ? k0 + 32 : k0;
#pragma unroll
    for (int i = 0; i < 2; ++i) {
      const int c = t + 256 * i, r = c >> 2, sg = c & 3;
      ph[i] = *(const f16x8*)&Hbh[(size_t)(row0 + r) * CHID + kn + sg * 8];
      pw[i] = *(const f16x8*)&Wt[(size_t)r * CHID + kn + sg * 8];
    }
    f16x8 af[4], bf[4];
#pragma unroll
    for (int i = 0; i < 4; ++i)
      af[i] = *(const f16x8*)&Hs[wr * 64 + i * 16 + lcol][quad * 8];
#pragma unroll
    for (int j = 0; j < 4; ++j)
      bf[j] = *(const f16x8*)&Ws[wc * 64 + j * 16 + lcol][quad * 8];
#pragma unroll
    for (int i = 0; i < 4; ++i)
#pragma unroll
      for (int j = 0; j < 4; ++j) acc[i][j] = mfma16(af[i], bf[j], acc[i][j]);
  }

#pragma unroll
  for (int i = 0; i < 4; ++i) {
#pragma unroll
    for (int rr = 0; rr < 4; ++rr) {
      const size_t rg = row0 + wr * 64 + i * 16 + quad * 4 + rr;
#pragma unroll
      for (int j = 0; j < 4; ++j)
        out[rg * CHID + col0 + wc * 64 + j * 16 + lcol] = acc[i][j][rr];
    }
  }
}

// ---------------------------------------------------------------------------
extern "C" void kernel_launch(void* const* d_in, const int* in_sizes, int n_in,
                              void* d_out, int out_size, void* d_ws,
                              size_t ws_size, hipStream_t stream) {
  const float* x = (const float*)d_in[0];
  const int* mask = (const int*)d_in[1];
  const float* Wq = (const float*)d_in[2];
  const float* Wk = (const float*)d_in[3];
  const float* Wv = (const float*)d_in[4];
  const float* Wout = (const float*)d_in[5];
  float* out = (float*)d_out;

  char* ws = (char*)d_ws;
  int* lens = (int*)ws;
  size_t off = 1024;
  const size_t NX = (size_t)CB * CS * CHID;   // 8,388,608
  const size_t NW = (size_t)CH * CHID * CDK;  // 262,144 per weight
  f16* xh = (f16*)(ws + off);    off += NX * 2;
  f16* wtAll = (f16*)(ws + off); off += NW * 4 * 2;
  f16* Qh = (f16*)(ws + off);    off += NX * 2;
  f16* Kh = (f16*)(ws + off);    off += NX * 2;
  f16* Vth = (f16*)(ws + off);   off += NX * 2;
  f16* Hbh = (f16*)(ws + off);   off += NX * 2;
  float* Vsum = (float*)(ws + off); off += (size_t)CB * CH * CDK * 4;
  f16* woutt = wtAll + NW * 3;

  lengths_kernel<<<CB, 256, 0, stream>>>(mask, lens, Vsum);
  cast_x_kernel<<<NX / 4 / 256, 256, 0, stream>>>((const float4*)x, (f16x4*)xh);
  cast_w_kernel<<<dim3(8, 32), 256, 0, stream>>>(Wq, Wk, Wv, Wout, wtAll);
  qkvf_kernel<<<dim3(128, 12), 256, 0, stream>>>(xh, wtAll, lens, Qh, Kh, Vth,
                                                 Vsum);
  attn_kernel<<<dim3(CS / 128, CH, CB), 256, 0, stream>>>(Qh, Kh, Vth, lens,
                                                          Vsum, Hbh);
  outp_kernel<<<dim3(128, 4), 256, 0, stream>>>(Hbh, woutt, out);
}